// Round 6
// baseline (214.674 us; speedup 1.0000x reference)
//
#include <hip/hip_runtime.h>
#include <hip/hip_fp16.h>
#include <math.h>

#define Bn 512
#define Ln 200
#define En 64
#define Hn 4
#define NITEMS (Bn * Hn)
#define KS3 18            // Kh/Qh row stride (halves): 36 B = 9 words (odd -> conflict-free)
#define VS3 200           // Vt row stride (halves): 100 words (2-way = free)
#define QSC 0.36067376022224085f   // 0.25 * log2(e): folds softmax exp into 2^x

typedef _Float16 __f16;
typedef __fp16 fp16x2 __attribute__((ext_vector_type(2)));   // native return type of cvt_pkrtz
typedef __f16 f16x4 __attribute__((ext_vector_type(4)));
typedef __f16 f16x8 __attribute__((ext_vector_type(8)));
typedef float f32x4 __attribute__((ext_vector_type(4)));

#if __has_builtin(__builtin_amdgcn_exp2f)
__device__ __forceinline__ float fexp2(float x) { return __builtin_amdgcn_exp2f(x); }
#else
__device__ __forceinline__ float fexp2(float x) { return exp2f(x); }
#endif

__device__ __forceinline__ f16x8 pack8s(float4 a, float4 b, float4 pa, float4 pb) {
    f16x8 r;
    r[0] = (__f16)(a.x + pa.x); r[1] = (__f16)(a.y + pa.y);
    r[2] = (__f16)(a.z + pa.z); r[3] = (__f16)(a.w + pa.w);
    r[4] = (__f16)(b.x + pb.x); r[5] = (__f16)(b.y + pb.y);
    r[6] = (__f16)(b.z + pb.z); r[7] = (__f16)(b.w + pb.w);
    return r;
}
__device__ __forceinline__ f16x8 pack8(float4 a, float4 b) {
    f16x8 r;
    r[0] = (__f16)a.x; r[1] = (__f16)a.y; r[2] = (__f16)a.z; r[3] = (__f16)a.w;
    r[4] = (__f16)b.x; r[5] = (__f16)b.y; r[6] = (__f16)b.z; r[7] = (__f16)b.w;
    return r;
}

// Pack 4 f32 -> f16x4 via two v_cvt_pkrtz_f16_f32 (2 converts/op instead of 4 scalar cvt).
__device__ __forceinline__ f16x4 pack4rtz(float e0, float e1, float e2, float e3) {
    const fp16x2 lo = __builtin_amdgcn_cvt_pkrtz(e0, e1);
    const fp16x2 hi = __builtin_amdgcn_cvt_pkrtz(e2, e3);
    f16x4 r;
    r[0] = (__f16)lo[0]; r[1] = (__f16)lo[1];
    r[2] = (__f16)hi[0]; r[3] = (__f16)hi[1];
    return r;
}

// Attention inner loop, trip-count-specialized on the number of LIVE q-tiles (NI).
template<int NI>
__device__ __forceinline__ void attn_core(
    const __f16* __restrict__ Kh_, const __f16* __restrict__ Qh_, const __f16* __restrict__ Vt_,
    int qt0, int klo, int khi, int nt, int len, int quad, int ln16,
    f32x4 (&o2)[4], f32x4 (&lacc)[4])
{
    const f16x4 ones = {(__f16)1.f, (__f16)1.f, (__f16)1.f, (__f16)1.f};
    f16x4 qf[NI];
    #pragma unroll
    for (int i = 0; i < NI; ++i) {
        int qr = min((qt0 + i) * 16 + ln16, Ln - 1);
        qf[i] = *(const f16x4*)(Qh_ + qr * KS3 + quad * 4);
    }
    const bool needmask = (khi == nt);
    const int kfull = khi - (needmask ? 1 : 0);

    f16x4 kf = *(const f16x4*)(Kh_ + min(klo * 16 + ln16, Ln - 1) * KS3 + quad * 4);
    f16x4 vf = *(const f16x4*)(Vt_ + ln16 * VS3 + min(klo * 16 + quad * 4, Ln - 4));

    for (int kt = klo; kt < kfull; ++kt) {   // full tiles: no masking
        const int krn = min((kt + 1) * 16 + ln16, Ln - 1);
        const int vcn = min((kt + 1) * 16 + quad * 4, Ln - 4);
        const f16x4 kfn = *(const f16x4*)(Kh_ + krn * KS3 + quad * 4);
        const f16x4 vfn = *(const f16x4*)(Vt_ + ln16 * VS3 + vcn);
        f32x4 s[NI];
        #pragma unroll
        for (int i = 0; i < NI; ++i)
            s[i] = __builtin_amdgcn_mfma_f32_16x16x16f16(kf, qf[i], (f32x4){0,0,0,0}, 0, 0, 0);
        f16x4 pf[NI];
        #pragma unroll
        for (int i = 0; i < NI; ++i) {
            pf[i] = pack4rtz(fexp2(fminf(s[i][0], 14.5f)),   // 2^14.5 < fp16 max
                             fexp2(fminf(s[i][1], 14.5f)),
                             fexp2(fminf(s[i][2], 14.5f)),
                             fexp2(fminf(s[i][3], 14.5f)));
        }
        #pragma unroll
        for (int i = 0; i < NI; ++i) {
            o2[i]   = __builtin_amdgcn_mfma_f32_16x16x16f16(vf,   pf[i], o2[i],   0, 0, 0);
            lacc[i] = __builtin_amdgcn_mfma_f32_16x16x16f16(ones, pf[i], lacc[i], 0, 0, 0);  // rowsum
        }
        kf = kfn; vf = vfn;
    }
    if (needmask) {   // last tile: zero keys >= len
        const int kbase = (nt - 1) * 16 + quad * 4;
        f32x4 s[NI];
        #pragma unroll
        for (int i = 0; i < NI; ++i)
            s[i] = __builtin_amdgcn_mfma_f32_16x16x16f16(kf, qf[i], (f32x4){0,0,0,0}, 0, 0, 0);
        f16x4 pf[NI];
        #pragma unroll
        for (int i = 0; i < NI; ++i) {
            float e[4];
            #pragma unroll
            for (int j = 0; j < 4; ++j) {
                const bool kok = (kbase + j) < len;
                e[j] = kok ? fexp2(fminf(s[i][j], 14.5f)) : 0.f;
            }
            pf[i] = pack4rtz(e[0], e[1], e[2], e[3]);
        }
        #pragma unroll
        for (int i = 0; i < NI; ++i) {
            o2[i]   = __builtin_amdgcn_mfma_f32_16x16x16f16(vf,   pf[i], o2[i],   0, 0, 0);
            lacc[i] = __builtin_amdgcn_mfma_f32_16x16x16f16(ones, pf[i], lacc[i], 0, 0, 0);
        }
    }
}

// ============ Persistent work-stealing: proj + attention + pool + Wf per item (b,h) ============
// R5: 512-thread blocks (8 waves), grid 1024 = 4 blocks/CU (32 waves = full cap). Each block
// pulls items off a global ticket -> perfect load balance (kills the static-assignment clumping
// tail). Per item: proj split 8 ways; heavy attention = 4 q-quads x 2 k-halves (critical path
// ~half of R3) with proj SHARED (unlike R2's failed split: zero duplicated work/fetch).
__global__ __launch_bounds__(512, 8) void fused_kernel(
    const float* __restrict__ input, const int* __restrict__ mask,
    const float* __restrict__ pos_enc,
    const float* __restrict__ Wk, const float* __restrict__ bk,
    const float* __restrict__ Wv, const float* __restrict__ bv,
    const float* __restrict__ Wq, const float* __restrict__ bq,
    const float* __restrict__ Wf, const float* __restrict__ bf_,
    float* __restrict__ out, int* __restrict__ ticket)
{
    __shared__ __align__(16) __f16 Kh[Ln * KS3];    // 7.2 KB  K[t][16]
    __shared__ __align__(16) __f16 Qh[Ln * KS3];    // 7.2 KB  Q[t][16] (pre-scaled QSC)
    __shared__ __align__(16) __f16 Vt[16 * VS3];    // 6.4 KB  V^T[vd][t]
    __shared__ float lred[8][4][16];                // 2 KB   partial softmax denominators
    __shared__ float red[8][16];
    __shared__ float ph[16];
    __shared__ int cnt_red[8];
    __shared__ int item_sh;

    const int tid  = threadIdx.x;
    const int wave = tid >> 6, lane = tid & 63;
    const int quad = lane >> 4, ln16 = lane & 15;
    const float4* pe4 = (const float4*)pos_enc;

    for (;;) {
        __syncthreads();   // protect LDS reuse from previous item's readers
        if (tid == 0) item_sh = atomicAdd(ticket, 1);
        __syncthreads();
        const int item = item_sh;
        if (item >= NITEMS) break;          // block-uniform exit
        const int b = item >> 2, h = item & 3;

        const float4* in4 = (const float4*)(input + (size_t)b * Ln * En);

        // ---- speculative first-tile input loads: wave 0 only (tile 0 always needed) ----
        float4 px0 = {0,0,0,0}, px1 = {0,0,0,0}, px2 = {0,0,0,0}, px3 = {0,0,0,0};
        if (wave == 0) {
            const int o4 = ln16 * 16 + quad * 2;      // rows 0..15, always valid
            px0 = in4[o4];     px1 = in4[o4 + 1];
            px2 = in4[o4 + 8]; px3 = in4[o4 + 9];
        }

        // ---- mask load (reduce is its first consumer) ----
        const int mv = (tid < Ln) ? mask[b * Ln + tid] : 0;

        // ---- weight B-fragments for THIS head (16 channels; L2-hot) + biases ----
        f16x8 bfr[3][2];
        #pragma unroll
        for (int m = 0; m < 3; ++m) {
            const float* W = (m == 0) ? Wk : (m == 1) ? Wv : Wq;
            #pragma unroll
            for (int ks = 0; ks < 2; ++ks) {
                const float4* wp = (const float4*)(W + (size_t)(h * 16 + ln16) * 64) + (ks * 8 + quad * 2);
                bfr[m][ks] = pack8(wp[0], wp[1]);
            }
        }
        const int cg = h * 16 + ln16;
        const float bkv = bk[cg], bvv = bv[cg], bqv = bq[cg];

        // ---- len (shuffle reduce over mask, 8 waves) ----
        int c = (mv != 0) ? 1 : 0;
        #pragma unroll
        for (int off = 32; off; off >>= 1) c += __shfl_down(c, off, 64);
        if (lane == 0) cnt_red[wave] = c;
        __syncthreads();
        int len = 0;
        #pragma unroll
        for (int w = 0; w < 8; ++w) len += cnt_red[w];
        const int nt = (len + 15) >> 4;

        // waves 1..7: first-tile load now that nt is known (rows <= 127 < Ln: safe)
        if (wave != 0 && wave < nt) {
            const int o4 = (wave * 16 + ln16) * 16 + quad * 2;
            px0 = in4[o4];     px1 = in4[o4 + 1];
            px2 = in4[o4 + 8]; px3 = in4[o4 + 9];
        }

        // ---- projection over nt tiles (8-way split; <=2 iters/wave), pipelined ----
        for (int rt = wave; rt < nt; rt += 8) {
            const int R = rt * 16 + ln16;
            const bool rok = (R < Ln);
            const int o4 = R * 16 + quad * 2;

            const int rtn = rt + 8;
            const int Rn = rtn * 16 + ln16;
            float4 pxn0 = {0,0,0,0}, pxn1 = {0,0,0,0}, pxn2 = {0,0,0,0}, pxn3 = {0,0,0,0};
            if (rtn < nt && Rn < Ln) {
                const int o4n = Rn * 16 + quad * 2;
                pxn0 = in4[o4n];     pxn1 = in4[o4n + 1];
                pxn2 = in4[o4n + 8]; pxn3 = in4[o4n + 9];
            }
            float4 pp0 = {0,0,0,0}, pp1 = {0,0,0,0}, pp2 = {0,0,0,0}, pp3 = {0,0,0,0};
            if (rok) {
                pp0 = pe4[o4];     pp1 = pe4[o4 + 1];
                pp2 = pe4[o4 + 8]; pp3 = pe4[o4 + 9];
            }
            const f16x8 af0 = pack8s(px0, px1, pp0, pp1);
            const f16x8 af1 = pack8s(px2, px3, pp2, pp3);

            f32x4 acc[3];
            #pragma unroll
            for (int m = 0; m < 3; ++m) acc[m] = (f32x4){0,0,0,0};
            #pragma unroll
            for (int m = 0; m < 3; ++m)
                acc[m] = __builtin_amdgcn_mfma_f32_16x16x32_f16(af0, bfr[m][0], acc[m], 0, 0, 0);
            #pragma unroll
            for (int m = 0; m < 3; ++m)
                acc[m] = __builtin_amdgcn_mfma_f32_16x16x32_f16(af1, bfr[m][1], acc[m], 0, 0, 0);

            #pragma unroll
            for (int j = 0; j < 4; ++j) {
                const int t = rt * 16 + quad * 4 + j;
                if (t < Ln) {
                    Kh[t * KS3 + ln16] = (__f16)(acc[0][j] + bkv);
                    Qh[t * KS3 + ln16] = (__f16)((acc[2][j] + bqv) * QSC);
                }
            }
            const int vc0 = rt * 16 + quad * 4;
            if (vc0 < Ln) {
                f16x4 vp;
                #pragma unroll
                for (int j = 0; j < 4; ++j) vp[j] = (__f16)(acc[1][j] + bvv);
                *(f16x4*)(Vt + ln16 * VS3 + vc0) = vp;
            }
            px0 = pxn0; px1 = pxn1; px2 = pxn2; px3 = pxn3;
        }
        __syncthreads();   // K/Q/V visible

        // ---- attention: 8-wave assignment over q-quads / key-splits ----
        // nquad >= 3 (nt 9..16): 4 q-quads x 2 k-halves     (nkh = 2)
        // nquad == 2 (nt 5..8):  2 q-quads x 4 k-quarters   (nkh = 4)
        // nquad == 1 (nt 1..4):  1 q-quad  x 8 k-eighths    (nkh = 8)
        const int nquad = (nt + 3) >> 2;
        int g, kh, nkh;
        if (nquad >= 3)      { g = wave & 3; kh = wave >> 2; nkh = 2; }
        else if (nquad == 2) { g = wave & 1; kh = wave >> 1; nkh = 4; }
        else                 { g = 0;        kh = wave;      nkh = 8; }
        const bool active = (g < nquad);
        const int nktp = (nt + nkh - 1) / nkh;
        const int klo = kh * nktp;
        const int khi = min(klo + nktp, nt);
        const int qt0 = 4 * g;

        f32x4 o2[4], lacc[4];
        #pragma unroll
        for (int i = 0; i < 4; ++i) { o2[i] = (f32x4){0,0,0,0}; lacc[i] = (f32x4){0,0,0,0}; }

        if (active && klo < khi) {
            const int ni = __builtin_amdgcn_readfirstlane(min(4, nt - qt0));
            switch (ni) {
                case 1:  attn_core<1>(Kh, Qh, Vt, qt0, klo, khi, nt, len, quad, ln16, o2, lacc); break;
                case 2:  attn_core<2>(Kh, Qh, Vt, qt0, klo, khi, nt, len, quad, ln16, o2, lacc); break;
                case 3:  attn_core<3>(Kh, Qh, Vt, qt0, klo, khi, nt, len, quad, ln16, o2, lacc); break;
                default: attn_core<4>(Kh, Qh, Vt, qt0, klo, khi, nt, len, quad, ln16, o2, lacc); break;
            }
        }

        // ---- denominators: lacc[i][0] = l[q=ln16] (replicated across rows by ones-MFMA) ----
        float l[4];
        #pragma unroll
        for (int i = 0; i < 4; ++i) l[i] = lacc[i][0];

        // exchange partial denominators across key-split waves (always nkh > 1 here)
        if (lane < 16) {
            #pragma unroll
            for (int i = 0; i < 4; ++i) lred[wave][i][lane] = l[i];
        }
        __syncthreads();
        #pragma unroll
        for (int i = 0; i < 4; ++i) {
            if (nkh == 2)      l[i] = lred[g][i][ln16] + lred[g + 4][i][ln16];
            else if (nkh == 4) l[i] = lred[g][i][ln16] + lred[g + 2][i][ln16]
                                    + lred[g + 4][i][ln16] + lred[g + 6][i][ln16];
            else {
                float s = 0.f;
                #pragma unroll
                for (int w = 0; w < 8; ++w) s += lred[w][i][ln16];
                l[i] = s;
            }
        }

        f32x4 pool = {0.f, 0.f, 0.f, 0.f};
        if (active) {
            #pragma unroll
            for (int i = 0; i < 4; ++i) {
                const float rs = ((qt0 + i) * 16 + ln16 < len) ? 1.f / l[i] : 0.f;
                #pragma unroll
                for (int j = 0; j < 4; ++j) pool[j] = fmaf(o2[i][j], rs, pool[j]);
            }
        }

        // ---- reduce pool over 16 q-lanes; combine 8 waves; write ----
        #pragma unroll
        for (int j = 0; j < 4; ++j) {
            #pragma unroll
            for (int off = 1; off < 16; off <<= 1) pool[j] += __shfl_xor(pool[j], off, 64);
        }
        if (ln16 == 0) {
            #pragma unroll
            for (int j = 0; j < 4; ++j) red[wave][quad * 4 + j] = pool[j];
        }
        __syncthreads();
        if (tid < 16) {
            float s = 0.f;
            #pragma unroll
            for (int w = 0; w < 8; ++w) s += red[w][tid];
            ph[tid] = s / ((float)len + 1e-8f);
        }
        __syncthreads();

        // ---- fused final projection: partial out[b,e] over i in [h*16, h*16+16) ----
        if (tid < 64) {
            const int e = tid;
            const float* wr = Wf + (size_t)e * 64 + h * 16;
            float a = (h == 0) ? bf_[e] : 0.f;
            #pragma unroll
            for (int i = 0; i < 16; ++i) a = fmaf(wr[i], ph[i], a);
            atomicAdd(out + b * En + e, a);
        }
    }
}

extern "C" void kernel_launch(void* const* d_in, const int* in_sizes, int n_in,
                              void* d_out, int out_size, void* d_ws, size_t ws_size,
                              hipStream_t stream) {
    const float* input   = (const float*)d_in[0];
    const int*   mask    = (const int*)  d_in[1];
    const float* pos_enc = (const float*)d_in[2];
    const float* Wk      = (const float*)d_in[3];
    const float* bk      = (const float*)d_in[4];
    const float* Wv      = (const float*)d_in[5];
    const float* bv      = (const float*)d_in[6];
    const float* Wq      = (const float*)d_in[7];
    const float* bq      = (const float*)d_in[8];
    const float* Wf      = (const float*)d_in[9];
    const float* bf      = (const float*)d_in[10];

    float* out    = (float*)d_out;
    int*   ticket = (int*)d_ws;

    hipMemsetAsync(out, 0, (size_t)Bn * En * sizeof(float), stream);   // zero accumulator
    hipMemsetAsync(ticket, 0, 64, stream);                             // zero work-steal ticket

    // 4 blocks/CU x 256 CU; extra blocks (if capacity differs) exit on empty ticket.
    fused_kernel<<<1024, 512, 0, stream>>>(input, mask, pos_enc,
                                           Wk, bk, Wv, bv, Wq, bq, Wf, bf,
                                           out, ticket);
}

// Round 7
// 146.573 us; speedup vs baseline: 1.4646x; 1.4646x over previous
//
#include <hip/hip_runtime.h>
#include <hip/hip_fp16.h>
#include <math.h>

#define Bn 512
#define Ln 200
#define En 64
#define Hn 4
#define NITEMS (Bn * Hn)
#define KS3 18            // Kh/Qh row stride (halves): 36 B = 9 words (odd -> conflict-free)
#define VS3 200           // Vt row stride (halves): 100 words (2-way = free)
#define QSC 0.36067376022224085f   // 0.25 * log2(e): folds softmax exp into 2^x

typedef _Float16 __f16;
typedef __fp16 fp16x2 __attribute__((ext_vector_type(2)));   // native return type of cvt_pkrtz
typedef __f16 f16x4 __attribute__((ext_vector_type(4)));
typedef __f16 f16x8 __attribute__((ext_vector_type(8)));
typedef float f32x4 __attribute__((ext_vector_type(4)));

#if __has_builtin(__builtin_amdgcn_exp2f)
__device__ __forceinline__ float fexp2(float x) { return __builtin_amdgcn_exp2f(x); }
#else
__device__ __forceinline__ float fexp2(float x) { return exp2f(x); }
#endif

__device__ __forceinline__ f16x8 pack8s(float4 a, float4 b, float4 pa, float4 pb) {
    f16x8 r;
    r[0] = (__f16)(a.x + pa.x); r[1] = (__f16)(a.y + pa.y);
    r[2] = (__f16)(a.z + pa.z); r[3] = (__f16)(a.w + pa.w);
    r[4] = (__f16)(b.x + pb.x); r[5] = (__f16)(b.y + pb.y);
    r[6] = (__f16)(b.z + pb.z); r[7] = (__f16)(b.w + pb.w);
    return r;
}
__device__ __forceinline__ f16x8 pack8(float4 a, float4 b) {
    f16x8 r;
    r[0] = (__f16)a.x; r[1] = (__f16)a.y; r[2] = (__f16)a.z; r[3] = (__f16)a.w;
    r[4] = (__f16)b.x; r[5] = (__f16)b.y; r[6] = (__f16)b.z; r[7] = (__f16)b.w;
    return r;
}

// Pack 4 f32 -> f16x4 via two v_cvt_pkrtz_f16_f32 (2 converts/op instead of 4 scalar cvt).
__device__ __forceinline__ f16x4 pack4rtz(float e0, float e1, float e2, float e3) {
    const fp16x2 lo = __builtin_amdgcn_cvt_pkrtz(e0, e1);
    const fp16x2 hi = __builtin_amdgcn_cvt_pkrtz(e2, e3);
    f16x4 r;
    r[0] = (__f16)lo[0]; r[1] = (__f16)lo[1];
    r[2] = (__f16)hi[0]; r[3] = (__f16)hi[1];
    return r;
}

// Attention inner loop, trip-count-specialized on the number of LIVE q-tiles (NI).
template<int NI>
__device__ __forceinline__ void attn_core(
    const __f16* __restrict__ Kh_, const __f16* __restrict__ Qh_, const __f16* __restrict__ Vt_,
    int qt0, int klo, int khi, int nt, int len, int quad, int ln16,
    f32x4 (&o2)[4], f32x4 (&lacc)[4])
{
    const f16x4 ones = {(__f16)1.f, (__f16)1.f, (__f16)1.f, (__f16)1.f};
    f16x4 qf[NI];
    #pragma unroll
    for (int i = 0; i < NI; ++i) {
        int qr = min((qt0 + i) * 16 + ln16, Ln - 1);
        qf[i] = *(const f16x4*)(Qh_ + qr * KS3 + quad * 4);
    }
    const bool needmask = (khi == nt);
    const int kfull = khi - (needmask ? 1 : 0);

    f16x4 kf = *(const f16x4*)(Kh_ + min(klo * 16 + ln16, Ln - 1) * KS3 + quad * 4);
    f16x4 vf = *(const f16x4*)(Vt_ + ln16 * VS3 + min(klo * 16 + quad * 4, Ln - 4));

    for (int kt = klo; kt < kfull; ++kt) {   // full tiles: no masking
        const int krn = min((kt + 1) * 16 + ln16, Ln - 1);
        const int vcn = min((kt + 1) * 16 + quad * 4, Ln - 4);
        const f16x4 kfn = *(const f16x4*)(Kh_ + krn * KS3 + quad * 4);
        const f16x4 vfn = *(const f16x4*)(Vt_ + ln16 * VS3 + vcn);
        f32x4 s[NI];
        #pragma unroll
        for (int i = 0; i < NI; ++i)
            s[i] = __builtin_amdgcn_mfma_f32_16x16x16f16(kf, qf[i], (f32x4){0,0,0,0}, 0, 0, 0);
        f16x4 pf[NI];
        #pragma unroll
        for (int i = 0; i < NI; ++i) {
            pf[i] = pack4rtz(fexp2(fminf(s[i][0], 14.5f)),   // 2^14.5 < fp16 max
                             fexp2(fminf(s[i][1], 14.5f)),
                             fexp2(fminf(s[i][2], 14.5f)),
                             fexp2(fminf(s[i][3], 14.5f)));
        }
        #pragma unroll
        for (int i = 0; i < NI; ++i) {
            o2[i]   = __builtin_amdgcn_mfma_f32_16x16x16f16(vf,   pf[i], o2[i],   0, 0, 0);
            lacc[i] = __builtin_amdgcn_mfma_f32_16x16x16f16(ones, pf[i], lacc[i], 0, 0, 0);  // rowsum
        }
        kf = kfn; vf = vfn;
    }
    if (needmask) {   // last tile: zero keys >= len
        const int kbase = (nt - 1) * 16 + quad * 4;
        f32x4 s[NI];
        #pragma unroll
        for (int i = 0; i < NI; ++i)
            s[i] = __builtin_amdgcn_mfma_f32_16x16x16f16(kf, qf[i], (f32x4){0,0,0,0}, 0, 0, 0);
        f16x4 pf[NI];
        #pragma unroll
        for (int i = 0; i < NI; ++i) {
            float e[4];
            #pragma unroll
            for (int j = 0; j < 4; ++j) {
                const bool kok = (kbase + j) < len;
                e[j] = kok ? fexp2(fminf(s[i][j], 14.5f)) : 0.f;
            }
            pf[i] = pack4rtz(e[0], e[1], e[2], e[3]);
        }
        #pragma unroll
        for (int i = 0; i < NI; ++i) {
            o2[i]   = __builtin_amdgcn_mfma_f32_16x16x16f16(vf,   pf[i], o2[i],   0, 0, 0);
            lacc[i] = __builtin_amdgcn_mfma_f32_16x16x16f16(ones, pf[i], lacc[i], 0, 0, 0);
        }
    }
}

// ============ Persistent work-stealing, 256-thr blocks: proj + attn + pool + Wf per item ============
// R6: R3's proven 4-wave/44-VGPR block body (fits the 8-waves/SIMD register budget; no spills),
// wrapped in a global-ticket persistent loop. Grid 1792 = 7 blocks/CU (LDS-capped) stays RESIDENT
// until the 2048-item pool drains -> occupancy holds near-full instead of draining from t=0.
// R5's spill run proved the BW ceiling is TLP-limited (3 TB/s at 71% occ vs 0.66 at 28%).
__global__ __launch_bounds__(256, 4) void fused_kernel(
    const float* __restrict__ input, const int* __restrict__ mask,
    const float* __restrict__ pos_enc,
    const float* __restrict__ Wk, const float* __restrict__ bk,
    const float* __restrict__ Wv, const float* __restrict__ bv,
    const float* __restrict__ Wq, const float* __restrict__ bq,
    const float* __restrict__ Wf, const float* __restrict__ bf_,
    float* __restrict__ out, int* __restrict__ ticket)
{
    __shared__ __align__(16) __f16 Kh[Ln * KS3];    // 7.2 KB  K[t][16]
    __shared__ __align__(16) __f16 Qh[Ln * KS3];    // 7.2 KB  Q[t][16] (pre-scaled QSC)
    __shared__ __align__(16) __f16 Vt[16 * VS3];    // 6.4 KB  V^T[vd][t]
    __shared__ float lred[4][4][16];                // 1 KB   partial softmax denominators
    __shared__ float red[4][16];
    __shared__ float ph[16];
    __shared__ int cnt_red[4];
    __shared__ int item_sh;

    const int tid  = threadIdx.x;
    const int wave = tid >> 6, lane = tid & 63;
    const int quad = lane >> 4, ln16 = lane & 15;
    const float4* pe4 = (const float4*)pos_enc;

    for (;;) {
        if (tid == 0) item_sh = atomicAdd(ticket, 1);
        __syncthreads();   // item visible; also fences LDS reuse from previous iteration
        const int item = item_sh;
        if (item >= NITEMS) break;          // block-uniform exit
        const int b = item >> 2, h = item & 3;

        const float4* in4 = (const float4*)(input + (size_t)b * Ln * En);

        // ---- speculative first-tile input loads: wave 0 only (tile 0 always needed) ----
        float4 px0 = {0,0,0,0}, px1 = {0,0,0,0}, px2 = {0,0,0,0}, px3 = {0,0,0,0};
        if (wave == 0) {
            const int o4 = ln16 * 16 + quad * 2;      // rows 0..15, always valid
            px0 = in4[o4];     px1 = in4[o4 + 1];
            px2 = in4[o4 + 8]; px3 = in4[o4 + 9];
        }

        // ---- mask load (reduce is its first consumer) ----
        const int mv = (tid < Ln) ? mask[b * Ln + tid] : 0;

        // ---- weight B-fragments for THIS head (16 channels; L2-hot) + biases ----
        f16x8 bfr[3][2];
        #pragma unroll
        for (int m = 0; m < 3; ++m) {
            const float* W = (m == 0) ? Wk : (m == 1) ? Wv : Wq;
            #pragma unroll
            for (int ks = 0; ks < 2; ++ks) {
                const float4* wp = (const float4*)(W + (size_t)(h * 16 + ln16) * 64) + (ks * 8 + quad * 2);
                bfr[m][ks] = pack8(wp[0], wp[1]);
            }
        }
        const int cg = h * 16 + ln16;
        const float bkv = bk[cg], bvv = bv[cg], bqv = bq[cg];

        // ---- len (shuffle reduce over mask) ----
        int c = (mv != 0) ? 1 : 0;
        #pragma unroll
        for (int off = 32; off; off >>= 1) c += __shfl_down(c, off, 64);
        if (lane == 0) cnt_red[wave] = c;
        __syncthreads();
        const int len = cnt_red[0] + cnt_red[1] + cnt_red[2] + cnt_red[3];
        const int nt = (len + 15) >> 4;

        // waves 1..3: first-tile load now that nt is known (rows <= 63 < Ln: safe)
        if (wave != 0 && wave < nt) {
            const int o4 = (wave * 16 + ln16) * 16 + quad * 2;
            px0 = in4[o4];     px1 = in4[o4 + 1];
            px2 = in4[o4 + 8]; px3 = in4[o4 + 9];
        }

        // ---- projection over nt tiles; software-pipelined input loads ----
        for (int rt = wave; rt < nt; rt += 4) {
            const int R = rt * 16 + ln16;
            const bool rok = (R < Ln);
            const int o4 = R * 16 + quad * 2;

            const int rtn = rt + 4;
            const int Rn = rtn * 16 + ln16;
            float4 pxn0 = {0,0,0,0}, pxn1 = {0,0,0,0}, pxn2 = {0,0,0,0}, pxn3 = {0,0,0,0};
            if (rtn < nt && Rn < Ln) {
                const int o4n = Rn * 16 + quad * 2;
                pxn0 = in4[o4n];     pxn1 = in4[o4n + 1];
                pxn2 = in4[o4n + 8]; pxn3 = in4[o4n + 9];
            }
            float4 pp0 = {0,0,0,0}, pp1 = {0,0,0,0}, pp2 = {0,0,0,0}, pp3 = {0,0,0,0};
            if (rok) {
                pp0 = pe4[o4];     pp1 = pe4[o4 + 1];
                pp2 = pe4[o4 + 8]; pp3 = pe4[o4 + 9];
            }
            const f16x8 af0 = pack8s(px0, px1, pp0, pp1);
            const f16x8 af1 = pack8s(px2, px3, pp2, pp3);

            f32x4 acc[3];
            #pragma unroll
            for (int m = 0; m < 3; ++m) acc[m] = (f32x4){0,0,0,0};
            #pragma unroll
            for (int m = 0; m < 3; ++m)
                acc[m] = __builtin_amdgcn_mfma_f32_16x16x32_f16(af0, bfr[m][0], acc[m], 0, 0, 0);
            #pragma unroll
            for (int m = 0; m < 3; ++m)
                acc[m] = __builtin_amdgcn_mfma_f32_16x16x32_f16(af1, bfr[m][1], acc[m], 0, 0, 0);

            #pragma unroll
            for (int j = 0; j < 4; ++j) {
                const int t = rt * 16 + quad * 4 + j;
                if (t < Ln) {
                    Kh[t * KS3 + ln16] = (__f16)(acc[0][j] + bkv);
                    Qh[t * KS3 + ln16] = (__f16)((acc[2][j] + bqv) * QSC);
                }
            }
            const int vc0 = rt * 16 + quad * 4;
            if (vc0 < Ln) {
                f16x4 vp;
                #pragma unroll
                for (int j = 0; j < 4; ++j) vp[j] = (__f16)(acc[1][j] + bvv);
                *(f16x4*)(Vt + ln16 * VS3 + vc0) = vp;
            }
            px0 = pxn0; px1 = pxn1; px2 = pxn2; px3 = pxn3;
        }
        __syncthreads();   // K/Q/V visible

        // ---- attention: adaptive wave assignment over q-quads / key-splits ----
        const int nquad = (nt + 3) >> 2;
        int g, kh, nkh;
        if (nquad >= 3)      { g = wave;     kh = 0;         nkh = 1; }
        else if (nquad == 2) { g = wave & 1; kh = wave >> 1; nkh = 2; }
        else                 { g = 0;        kh = wave;      nkh = 4; }
        const bool active = (g < nquad);
        const int nktp = (nt + nkh - 1) / nkh;
        const int klo = kh * nktp;
        const int khi = min(klo + nktp, nt);
        const int qt0 = 4 * g;

        f32x4 o2[4], lacc[4];
        #pragma unroll
        for (int i = 0; i < 4; ++i) { o2[i] = (f32x4){0,0,0,0}; lacc[i] = (f32x4){0,0,0,0}; }

        if (active && klo < khi) {
            const int ni = __builtin_amdgcn_readfirstlane(min(4, nt - qt0));
            switch (ni) {
                case 1:  attn_core<1>(Kh, Qh, Vt, qt0, klo, khi, nt, len, quad, ln16, o2, lacc); break;
                case 2:  attn_core<2>(Kh, Qh, Vt, qt0, klo, khi, nt, len, quad, ln16, o2, lacc); break;
                case 3:  attn_core<3>(Kh, Qh, Vt, qt0, klo, khi, nt, len, quad, ln16, o2, lacc); break;
                default: attn_core<4>(Kh, Qh, Vt, qt0, klo, khi, nt, len, quad, ln16, o2, lacc); break;
            }
        }

        // ---- denominators: lacc[i][0] = l[q=ln16] (replicated across rows by ones-MFMA) ----
        float l[4];
        #pragma unroll
        for (int i = 0; i < 4; ++i) l[i] = lacc[i][0];

        if (nkh > 1) {   // block-uniform: exchange partial denominators across key-split waves
            if (lane < 16) {
                #pragma unroll
                for (int i = 0; i < 4; ++i) lred[wave][i][lane] = l[i];
            }
            __syncthreads();
            #pragma unroll
            for (int i = 0; i < 4; ++i) {
                if (nkh == 2) l[i] = lred[g][i][ln16] + lred[g + 2][i][ln16];
                else          l[i] = lred[0][i][ln16] + lred[1][i][ln16]
                                   + lred[2][i][ln16] + lred[3][i][ln16];
            }
        }

        f32x4 pool = {0.f, 0.f, 0.f, 0.f};
        if (active) {
            #pragma unroll
            for (int i = 0; i < 4; ++i) {
                const float rs = ((qt0 + i) * 16 + ln16 < len) ? 1.f / l[i] : 0.f;
                #pragma unroll
                for (int j = 0; j < 4; ++j) pool[j] = fmaf(o2[i][j], rs, pool[j]);
            }
        }

        // ---- reduce pool over 16 q-lanes; combine 4 waves; write ----
        #pragma unroll
        for (int j = 0; j < 4; ++j) {
            #pragma unroll
            for (int off = 1; off < 16; off <<= 1) pool[j] += __shfl_xor(pool[j], off, 64);
        }
        if (ln16 == 0) {
            #pragma unroll
            for (int j = 0; j < 4; ++j) red[wave][quad * 4 + j] = pool[j];
        }
        __syncthreads();
        if (tid < 16)
            ph[tid] = (red[0][tid] + red[1][tid] + red[2][tid] + red[3][tid]) / ((float)len + 1e-8f);
        __syncthreads();

        // ---- fused final projection: partial out[b,e] over i in [h*16, h*16+16) ----
        if (tid < 64) {
            const int e = tid;
            const float* wr = Wf + (size_t)e * 64 + h * 16;
            float a = (h == 0) ? bf_[e] : 0.f;
            #pragma unroll
            for (int i = 0; i < 16; ++i) a = fmaf(wr[i], ph[i], a);
            atomicAdd(out + b * En + e, a);
        }
        __syncthreads();   // out/ph consumed; safe to overwrite LDS next item
    }
}

extern "C" void kernel_launch(void* const* d_in, const int* in_sizes, int n_in,
                              void* d_out, int out_size, void* d_ws, size_t ws_size,
                              hipStream_t stream) {
    const float* input   = (const float*)d_in[0];
    const int*   mask    = (const int*)  d_in[1];
    const float* pos_enc = (const float*)d_in[2];
    const float* Wk      = (const float*)d_in[3];
    const float* bk      = (const float*)d_in[4];
    const float* Wv      = (const float*)d_in[5];
    const float* bv      = (const float*)d_in[6];
    const float* Wq      = (const float*)d_in[7];
    const float* bq      = (const float*)d_in[8];
    const float* Wf      = (const float*)d_in[9];
    const float* bf      = (const float*)d_in[10];

    float* out    = (float*)d_out;
    int*   ticket = (int*)d_ws;

    hipMemsetAsync(out, 0, (size_t)Bn * En * sizeof(float), stream);   // zero accumulator
    hipMemsetAsync(ticket, 0, 64, stream);                             // zero work-steal ticket

    // 7 blocks/CU (LDS-capped) x 256 CU persistent blocks; they drain the 2048-item ticket.
    fused_kernel<<<1792, 256, 0, stream>>>(input, mask, pos_enc,
                                           Wk, bk, Wv, bv, Wq, bq, Wf, bf,
                                           out, ticket);
}

// Round 8
// 144.075 us; speedup vs baseline: 1.4900x; 1.0173x over previous
//
#include <hip/hip_runtime.h>
#include <hip/hip_fp16.h>
#include <math.h>

#define Bn 512
#define Ln 200
#define En 64
#define Hn 4
#define NITEMS (Bn * Hn)
#define GRID 768          // 3 blocks/CU x 256 CU
#define KS3 18            // Kh/Qh row stride (halves): 36 B = 9 words (odd -> conflict-free)
#define VS3 200           // Vt row stride (halves): 100 words (2-way = free)
#define QSC 0.36067376022224085f   // 0.25 * log2(e): folds softmax exp into 2^x

typedef _Float16 __f16;
typedef __fp16 fp16x2 __attribute__((ext_vector_type(2)));   // native return type of cvt_pkrtz
typedef __f16 f16x4 __attribute__((ext_vector_type(4)));
typedef __f16 f16x8 __attribute__((ext_vector_type(8)));
typedef float f32x4 __attribute__((ext_vector_type(4)));

#if __has_builtin(__builtin_amdgcn_exp2f)
__device__ __forceinline__ float fexp2(float x) { return __builtin_amdgcn_exp2f(x); }
#else
__device__ __forceinline__ float fexp2(float x) { return exp2f(x); }
#endif

__device__ __forceinline__ f16x8 pack8s(float4 a, float4 b, float4 pa, float4 pb) {
    f16x8 r;
    r[0] = (__f16)(a.x + pa.x); r[1] = (__f16)(a.y + pa.y);
    r[2] = (__f16)(a.z + pa.z); r[3] = (__f16)(a.w + pa.w);
    r[4] = (__f16)(b.x + pb.x); r[5] = (__f16)(b.y + pb.y);
    r[6] = (__f16)(b.z + pb.z); r[7] = (__f16)(b.w + pb.w);
    return r;
}
__device__ __forceinline__ f16x8 pack8(float4 a, float4 b) {
    f16x8 r;
    r[0] = (__f16)a.x; r[1] = (__f16)a.y; r[2] = (__f16)a.z; r[3] = (__f16)a.w;
    r[4] = (__f16)b.x; r[5] = (__f16)b.y; r[6] = (__f16)b.z; r[7] = (__f16)b.w;
    return r;
}

// Pack 4 f32 -> f16x4 via two v_cvt_pkrtz_f16_f32 (2 converts/op instead of 4 scalar cvt).
__device__ __forceinline__ f16x4 pack4rtz(float e0, float e1, float e2, float e3) {
    const fp16x2 lo = __builtin_amdgcn_cvt_pkrtz(e0, e1);
    const fp16x2 hi = __builtin_amdgcn_cvt_pkrtz(e2, e3);
    f16x4 r;
    r[0] = (__f16)lo[0]; r[1] = (__f16)lo[1];
    r[2] = (__f16)hi[0]; r[3] = (__f16)hi[1];
    return r;
}

// Attention inner loop, trip-count-specialized on the number of LIVE q-tiles (NI).
template<int NI>
__device__ __forceinline__ void attn_core(
    const __f16* __restrict__ Kh_, const __f16* __restrict__ Qh_, const __f16* __restrict__ Vt_,
    int qt0, int klo, int khi, int nt, int len, int quad, int ln16,
    f32x4 (&o2)[4], f32x4 (&lacc)[4])
{
    const f16x4 ones = {(__f16)1.f, (__f16)1.f, (__f16)1.f, (__f16)1.f};
    f16x4 qf[NI];
    #pragma unroll
    for (int i = 0; i < NI; ++i) {
        int qr = min((qt0 + i) * 16 + ln16, Ln - 1);
        qf[i] = *(const f16x4*)(Qh_ + qr * KS3 + quad * 4);
    }
    const bool needmask = (khi == nt);
    const int kfull = khi - (needmask ? 1 : 0);

    f16x4 kf = *(const f16x4*)(Kh_ + min(klo * 16 + ln16, Ln - 1) * KS3 + quad * 4);
    f16x4 vf = *(const f16x4*)(Vt_ + ln16 * VS3 + min(klo * 16 + quad * 4, Ln - 4));

    for (int kt = klo; kt < kfull; ++kt) {   // full tiles: no masking
        const int krn = min((kt + 1) * 16 + ln16, Ln - 1);
        const int vcn = min((kt + 1) * 16 + quad * 4, Ln - 4);
        const f16x4 kfn = *(const f16x4*)(Kh_ + krn * KS3 + quad * 4);
        const f16x4 vfn = *(const f16x4*)(Vt_ + ln16 * VS3 + vcn);
        f32x4 s[NI];
        #pragma unroll
        for (int i = 0; i < NI; ++i)
            s[i] = __builtin_amdgcn_mfma_f32_16x16x16f16(kf, qf[i], (f32x4){0,0,0,0}, 0, 0, 0);
        f16x4 pf[NI];
        #pragma unroll
        for (int i = 0; i < NI; ++i) {
            pf[i] = pack4rtz(fexp2(fminf(s[i][0], 14.5f)),   // 2^14.5 < fp16 max
                             fexp2(fminf(s[i][1], 14.5f)),
                             fexp2(fminf(s[i][2], 14.5f)),
                             fexp2(fminf(s[i][3], 14.5f)));
        }
        #pragma unroll
        for (int i = 0; i < NI; ++i) {
            o2[i]   = __builtin_amdgcn_mfma_f32_16x16x16f16(vf,   pf[i], o2[i],   0, 0, 0);
            lacc[i] = __builtin_amdgcn_mfma_f32_16x16x16f16(ones, pf[i], lacc[i], 0, 0, 0);  // rowsum
        }
        kf = kfn; vf = vfn;
    }
    if (needmask) {   // last tile: zero keys >= len
        const int kbase = (nt - 1) * 16 + quad * 4;
        f32x4 s[NI];
        #pragma unroll
        for (int i = 0; i < NI; ++i)
            s[i] = __builtin_amdgcn_mfma_f32_16x16x16f16(kf, qf[i], (f32x4){0,0,0,0}, 0, 0, 0);
        f16x4 pf[NI];
        #pragma unroll
        for (int i = 0; i < NI; ++i) {
            float e[4];
            #pragma unroll
            for (int j = 0; j < 4; ++j) {
                const bool kok = (kbase + j) < len;
                e[j] = kok ? fexp2(fminf(s[i][j], 14.5f)) : 0.f;
            }
            pf[i] = pack4rtz(e[0], e[1], e[2], e[3]);
        }
        #pragma unroll
        for (int i = 0; i < NI; ++i) {
            o2[i]   = __builtin_amdgcn_mfma_f32_16x16x16f16(vf,   pf[i], o2[i],   0, 0, 0);
            lacc[i] = __builtin_amdgcn_mfma_f32_16x16x16f16(ones, pf[i], lacc[i], 0, 0, 0);
        }
    }
}

// ============ Producer-consumer crews: proj(item k+1) || attn(item k), double-buffered LDS ============
// R7: 512 threads = 2 crews of 4 waves. Proj crew projects item k+1 into buf[(k+1)&1] while attn
// crew consumes item k from buf[k&1]; ONE __syncthreads per item swaps. Proj crew is continuously
// issuing global loads (high memory duty - the R5 spill run proved rate scales with loads in
// flight); proj and attn now overlap (wall -> max, not sum). Crews are internally barrier-free:
// per-wave len reduce; attn waves own a full q-quad (no lred); per-wave pool->Wf via shfl +
// per-wave LDS scratch + per-wave atomicAdd partials (exact by linearity).
__global__ __launch_bounds__(512, 6) void fused_kernel(
    const float* __restrict__ input, const int* __restrict__ mask,
    const float* __restrict__ pos_enc,
    const float* __restrict__ Wk, const float* __restrict__ bk,
    const float* __restrict__ Wv, const float* __restrict__ bv,
    const float* __restrict__ Wq, const float* __restrict__ bq,
    const float* __restrict__ Wf, const float* __restrict__ bf_,
    float* __restrict__ out)
{
    __shared__ __align__(16) __f16 KhB[2][Ln * KS3];   // 2 x 7.2 KB
    __shared__ __align__(16) __f16 QhB[2][Ln * KS3];   // 2 x 7.2 KB
    __shared__ __align__(16) __f16 VtB[2][16 * VS3];   // 2 x 6.4 KB
    __shared__ float swr[4][16];                       // per-attn-wave scratch (no barrier use)
    __shared__ int meta[2];                            // len per buffer

    const int tid  = threadIdx.x;
    const int crew = tid >> 8;          // 0 = proj waves 0-3, 1 = attn waves 4-7
    const int wv   = (tid >> 6) & 3;    // crew-local wave
    const int lane = tid & 63;
    const int quad = lane >> 4, ln16 = lane & 15;

    // XCD swizzle (768 = 8 x 96, bijective): consecutive lin (= consecutive items incl. the
    // 4 heads of one b) land on the same XCD -> input[b] re-reads are L2 hits.
    const int lin = (blockIdx.x & 7) * (GRID / 8) + (blockIdx.x >> 3);
    const int m   = (lin < NITEMS - 2 * GRID) ? 3 : 2;   // items: lin + r*GRID, r = 0..m-1

    const float4* pe4 = (const float4*)pos_enc;

    for (int j = -1; j < m; ++j) {
        if (crew == 0) {
            // ================= producer: project item I_{j+1} into buf[(j+1)&1] =================
            const int r = j + 1;
            if (r < m) {
                const int item = lin + r * GRID;
                const int b = item >> 2, h = item & 3;
                __f16* Kh = KhB[r & 1];
                __f16* Qh = QhB[r & 1];
                __f16* Vt = VtB[r & 1];
                const float4* in4 = (const float4*)(input + (size_t)b * Ln * En);

                // ---- len: wave-local full-mask reduce (no cross-wave barrier) ----
                const int* mb = mask + b * Ln;
                int c = (mb[lane] != 0) + (mb[64 + lane] != 0) + (mb[128 + lane] != 0)
                      + ((lane < Ln - 192) ? (mb[192 + lane] != 0) : 0);
                #pragma unroll
                for (int off = 32; off; off >>= 1) c += __shfl_down(c, off, 64);
                const int len = __shfl(c, 0, 64);
                const int nt = (len + 15) >> 4;
                if (tid == 0) meta[r & 1] = len;

                // ---- weight B-fragments for THIS head + biases (L2-hot) ----
                f16x8 bfr[3][2];
                #pragma unroll
                for (int mm = 0; mm < 3; ++mm) {
                    const float* W = (mm == 0) ? Wk : (mm == 1) ? Wv : Wq;
                    #pragma unroll
                    for (int ks = 0; ks < 2; ++ks) {
                        const float4* wp = (const float4*)(W + (size_t)(h * 16 + ln16) * 64) + (ks * 8 + quad * 2);
                        bfr[mm][ks] = pack8(wp[0], wp[1]);
                    }
                }
                const int cg = h * 16 + ln16;
                const float bkv = bk[cg], bvv = bv[cg], bqv = bq[cg];

                // ---- projection over nt tiles ----
                for (int rt = wv; rt < nt; rt += 4) {
                    const int R = rt * 16 + ln16;
                    const bool rok = (R < Ln);
                    const int o4 = R * 16 + quad * 2;
                    float4 xa = {0,0,0,0}, xb = {0,0,0,0}, xc = {0,0,0,0}, xd = {0,0,0,0};
                    float4 pa = {0,0,0,0}, pb = {0,0,0,0}, pc = {0,0,0,0}, pd = {0,0,0,0};
                    if (rok) {
                        xa = in4[o4];     xb = in4[o4 + 1];
                        xc = in4[o4 + 8]; xd = in4[o4 + 9];
                        pa = pe4[o4];     pb = pe4[o4 + 1];
                        pc = pe4[o4 + 8]; pd = pe4[o4 + 9];
                    }
                    const f16x8 af0 = pack8s(xa, xb, pa, pb);
                    const f16x8 af1 = pack8s(xc, xd, pc, pd);

                    f32x4 acc[3];
                    #pragma unroll
                    for (int mm = 0; mm < 3; ++mm) acc[mm] = (f32x4){0,0,0,0};
                    #pragma unroll
                    for (int mm = 0; mm < 3; ++mm)
                        acc[mm] = __builtin_amdgcn_mfma_f32_16x16x32_f16(af0, bfr[mm][0], acc[mm], 0, 0, 0);
                    #pragma unroll
                    for (int mm = 0; mm < 3; ++mm)
                        acc[mm] = __builtin_amdgcn_mfma_f32_16x16x32_f16(af1, bfr[mm][1], acc[mm], 0, 0, 0);

                    #pragma unroll
                    for (int jj = 0; jj < 4; ++jj) {
                        const int t = rt * 16 + quad * 4 + jj;
                        if (t < Ln) {
                            Kh[t * KS3 + ln16] = (__f16)(acc[0][jj] + bkv);
                            Qh[t * KS3 + ln16] = (__f16)((acc[2][jj] + bqv) * QSC);
                        }
                    }
                    const int vc0 = rt * 16 + quad * 4;
                    if (vc0 < Ln) {
                        f16x4 vp;
                        #pragma unroll
                        for (int jj = 0; jj < 4; ++jj) vp[jj] = (__f16)(acc[1][jj] + bvv);
                        *(f16x4*)(Vt + ln16 * VS3 + vc0) = vp;
                    }
                }
            }
        } else {
            // ================= consumer: attention + pool + Wf on item I_j from buf[j&1] =================
            if (j >= 0) {
                const int item = lin + j * GRID;
                const int b = item >> 2, h = item & 3;
                const __f16* Kh = KhB[j & 1];
                const __f16* Qh = QhB[j & 1];
                const __f16* Vt = VtB[j & 1];
                const int len = meta[j & 1];
                const int nt = (len + 15) >> 4;
                const int nquad = (nt + 3) >> 2;
                const int g = wv;                 // each attn wave owns ONE q-quad, all keys
                const int qt0 = 4 * g;
                const bool active = (g < nquad);

                f32x4 o2[4], lacc[4];
                #pragma unroll
                for (int i = 0; i < 4; ++i) { o2[i] = (f32x4){0,0,0,0}; lacc[i] = (f32x4){0,0,0,0}; }

                if (active) {
                    const int ni = __builtin_amdgcn_readfirstlane(min(4, nt - qt0));
                    switch (ni) {
                        case 1:  attn_core<1>(Kh, Qh, Vt, qt0, 0, nt, nt, len, quad, ln16, o2, lacc); break;
                        case 2:  attn_core<2>(Kh, Qh, Vt, qt0, 0, nt, nt, len, quad, ln16, o2, lacc); break;
                        case 3:  attn_core<3>(Kh, Qh, Vt, qt0, 0, nt, nt, len, quad, ln16, o2, lacc); break;
                        default: attn_core<4>(Kh, Qh, Vt, qt0, 0, nt, nt, len, quad, ln16, o2, lacc); break;
                    }
                }

                // denominators are wave-local (nkh == 1): lacc[i][0] = l[q = ln16]
                f32x4 pool = {0.f, 0.f, 0.f, 0.f};
                if (active) {
                    #pragma unroll
                    for (int i = 0; i < 4; ++i) {
                        const float rs = ((qt0 + i) * 16 + ln16 < len) ? 1.f / lacc[i][0] : 0.f;
                        #pragma unroll
                        for (int jj = 0; jj < 4; ++jj) pool[jj] = fmaf(o2[i][jj], rs, pool[jj]);
                    }
                }
                // reduce over the 16 q-lanes of each quad group
                #pragma unroll
                for (int jj = 0; jj < 4; ++jj) {
                    #pragma unroll
                    for (int off = 1; off < 16; off <<= 1) pool[jj] += __shfl_xor(pool[jj], off, 64);
                }
                // wave-internal LDS transpose (same-wave RAW: compiler-ordered, no barrier)
                if (ln16 == 0) {
                    #pragma unroll
                    for (int jj = 0; jj < 4; ++jj) swr[wv][quad * 4 + jj] = pool[jj];
                }
                float phv[16];
                #pragma unroll
                for (int i = 0; i < 16; ++i) phv[i] = swr[wv][i];

                // per-wave partial of out[b, e=lane] (linear in pool partials -> exact)
                const float invlen = 1.f / ((float)len + 1e-8f);
                const float* wr = Wf + (size_t)lane * En + h * 16;
                float a = 0.f;
                #pragma unroll
                for (int i = 0; i < 16; ++i) a = fmaf(wr[i], phv[i], a);
                a *= invlen;
                if (h == 0 && wv == 0) a += bf_[lane];    // bias added exactly once per b
                atomicAdd(out + b * En + lane, a);
            }
        }
        __syncthreads();   // swap buffers: proj writes of buf[(j+1)&1] visible; attn done with buf[j&1]
    }
}

extern "C" void kernel_launch(void* const* d_in, const int* in_sizes, int n_in,
                              void* d_out, int out_size, void* d_ws, size_t ws_size,
                              hipStream_t stream) {
    const float* input   = (const float*)d_in[0];
    const int*   mask    = (const int*)  d_in[1];
    const float* pos_enc = (const float*)d_in[2];
    const float* Wk      = (const float*)d_in[3];
    const float* bk      = (const float*)d_in[4];
    const float* Wv      = (const float*)d_in[5];
    const float* bv      = (const float*)d_in[6];
    const float* Wq      = (const float*)d_in[7];
    const float* bq      = (const float*)d_in[8];
    const float* Wf      = (const float*)d_in[9];
    const float* bf      = (const float*)d_in[10];

    float* out = (float*)d_out;
    hipMemsetAsync(out, 0, (size_t)Bn * En * sizeof(float), stream);   // zero accumulator

    fused_kernel<<<GRID, 512, 0, stream>>>(input, mask, pos_enc,
                                           Wk, bk, Wv, bv, Wq, bq, Wf, bf, out);
}

// Round 9
// 125.228 us; speedup vs baseline: 1.7143x; 1.1505x over previous
//
#include <hip/hip_runtime.h>
#include <hip/hip_fp16.h>
#include <math.h>

#define Bn 512
#define Ln 200
#define En 64
#define Hn 4
#define KS 16             // K/Q row stride (halves): 32B rows -> bank rotation 8/row, floor-optimal b64 reads
#define VS 200            // Vt row stride (halves)
#define QSC 0.36067376022224085f   // 0.25 * log2(e): folds softmax exp into 2^x

typedef _Float16 __f16;
typedef __fp16 fp16x2 __attribute__((ext_vector_type(2)));   // native return type of cvt_pkrtz
typedef __f16 f16x4 __attribute__((ext_vector_type(4)));
typedef __f16 f16x8 __attribute__((ext_vector_type(8)));
typedef float f32x4 __attribute__((ext_vector_type(4)));

#if __has_builtin(__builtin_amdgcn_exp2f)
__device__ __forceinline__ float fexp2(float x) { return __builtin_amdgcn_exp2f(x); }
#else
__device__ __forceinline__ float fexp2(float x) { return exp2f(x); }
#endif

__device__ __forceinline__ f16x8 pack8s(float4 a, float4 b, float4 pa, float4 pb) {
    f16x8 r;
    r[0] = (__f16)(a.x + pa.x); r[1] = (__f16)(a.y + pa.y);
    r[2] = (__f16)(a.z + pa.z); r[3] = (__f16)(a.w + pa.w);
    r[4] = (__f16)(b.x + pb.x); r[5] = (__f16)(b.y + pb.y);
    r[6] = (__f16)(b.z + pb.z); r[7] = (__f16)(b.w + pb.w);
    return r;
}
__device__ __forceinline__ f16x8 pack8(float4 a, float4 b) {
    f16x8 r;
    r[0] = (__f16)a.x; r[1] = (__f16)a.y; r[2] = (__f16)a.z; r[3] = (__f16)a.w;
    r[4] = (__f16)b.x; r[5] = (__f16)b.y; r[6] = (__f16)b.z; r[7] = (__f16)b.w;
    return r;
}

// Pack 4 f32 -> f16x4 via two v_cvt_pkrtz_f16_f32.
__device__ __forceinline__ f16x4 pack4rtz(float e0, float e1, float e2, float e3) {
    const fp16x2 lo = __builtin_amdgcn_cvt_pkrtz(e0, e1);
    const fp16x2 hi = __builtin_amdgcn_cvt_pkrtz(e2, e3);
    f16x4 r;
    r[0] = (__f16)lo[0]; r[1] = (__f16)lo[1];
    r[2] = (__f16)hi[0]; r[3] = (__f16)hi[1];
    return r;
}

// Attention inner loop over ALL keys for one q-quad (4 q-tiles max), NI = live q-tiles.
template<int NI>
__device__ __forceinline__ void attn_core(
    const __f16* __restrict__ Kh_, const __f16* __restrict__ Qh_, const __f16* __restrict__ Vt_,
    int qt0, int nt, int len, int quad, int ln16,
    f32x4 (&o2)[4], f32x4 (&lacc)[4])
{
    const f16x4 ones = {(__f16)1.f, (__f16)1.f, (__f16)1.f, (__f16)1.f};
    f16x4 qf[NI];
    #pragma unroll
    for (int i = 0; i < NI; ++i) {
        int qr = min((qt0 + i) * 16 + ln16, Ln - 1);
        qf[i] = *(const f16x4*)(Qh_ + qr * KS + quad * 4);
    }
    const int kfull = nt - 1;   // all but last tile need no masking

    f16x4 kf = *(const f16x4*)(Kh_ + ln16 * KS + quad * 4);
    f16x4 vf = *(const f16x4*)(Vt_ + ln16 * VS + quad * 4);

    for (int kt = 0; kt < kfull; ++kt) {
        const int krn = min((kt + 1) * 16 + ln16, Ln - 1);
        const int vcn = min((kt + 1) * 16 + quad * 4, Ln - 4);
        const f16x4 kfn = *(const f16x4*)(Kh_ + krn * KS + quad * 4);
        const f16x4 vfn = *(const f16x4*)(Vt_ + ln16 * VS + vcn);
        f32x4 s[NI];
        #pragma unroll
        for (int i = 0; i < NI; ++i)
            s[i] = __builtin_amdgcn_mfma_f32_16x16x16f16(kf, qf[i], (f32x4){0,0,0,0}, 0, 0, 0);
        f16x4 pf[NI];
        #pragma unroll
        for (int i = 0; i < NI; ++i) {
            pf[i] = pack4rtz(fexp2(fminf(s[i][0], 14.5f)),   // 2^14.5 < fp16 max
                             fexp2(fminf(s[i][1], 14.5f)),
                             fexp2(fminf(s[i][2], 14.5f)),
                             fexp2(fminf(s[i][3], 14.5f)));
        }
        #pragma unroll
        for (int i = 0; i < NI; ++i) {
            o2[i]   = __builtin_amdgcn_mfma_f32_16x16x16f16(vf,   pf[i], o2[i],   0, 0, 0);
            lacc[i] = __builtin_amdgcn_mfma_f32_16x16x16f16(ones, pf[i], lacc[i], 0, 0, 0);  // rowsum
        }
        kf = kfn; vf = vfn;
    }
    {   // last key tile: zero keys >= len
        const int kbase = (nt - 1) * 16 + quad * 4;
        f32x4 s[NI];
        #pragma unroll
        for (int i = 0; i < NI; ++i)
            s[i] = __builtin_amdgcn_mfma_f32_16x16x16f16(kf, qf[i], (f32x4){0,0,0,0}, 0, 0, 0);
        f16x4 pf[NI];
        #pragma unroll
        for (int i = 0; i < NI; ++i) {
            float e[4];
            #pragma unroll
            for (int j = 0; j < 4; ++j) {
                const bool kok = (kbase + j) < len;
                e[j] = kok ? fexp2(fminf(s[i][j], 14.5f)) : 0.f;
            }
            pf[i] = pack4rtz(e[0], e[1], e[2], e[3]);
        }
        #pragma unroll
        for (int i = 0; i < NI; ++i) {
            o2[i]   = __builtin_amdgcn_mfma_f32_16x16x16f16(vf,   pf[i], o2[i],   0, 0, 0);
            lacc[i] = __builtin_amdgcn_mfma_f32_16x16x16f16(ones, pf[i], lacc[i], 0, 0, 0);
        }
    }
}

// ============ One block per b: merged 4-head proj + attention + pool + Wf ============
// R8: x is loaded ONCE per b (was 4x: one per head-block). Proj feeds each x A-fragment to all
// 4 heads' B-fragments (24 MFMAs/tile) -> 4x fewer global load instructions chip-wide, which is
// the wall (wall ~ load-work / concurrency; R5 spill run + R6 ticket run calibrated the model).
// Fat waves replace wave-count: launch_bounds(256,2) gives ~256 VGPR so bfr[3][4][2] (96 regs)
// + acc (48) + x pipeline live without spill. LDS 76.8KB -> 2 blocks/CU.
__global__ __launch_bounds__(256, 2) void fused_kernel(
    const float* __restrict__ input, const int* __restrict__ mask,
    const float* __restrict__ pos_enc,
    const float* __restrict__ Wk, const float* __restrict__ bk,
    const float* __restrict__ Wv, const float* __restrict__ bv,
    const float* __restrict__ Wq, const float* __restrict__ bq,
    const float* __restrict__ Wf, const float* __restrict__ bf_,
    float* __restrict__ out)
{
    __shared__ __align__(16) __f16 KhA[Hn][Ln * KS];   // 25.6 KB  K[h][t][16]
    __shared__ __align__(16) __f16 QhA[Hn][Ln * KS];   // 25.6 KB  Q[h][t][16] (pre-scaled QSC)
    __shared__ __align__(16) __f16 VtA[Hn][16 * VS];   // 25.6 KB  V^T[h][vd][t]
    __shared__ float swr[4][16];                        // per-wave pool transpose scratch
    __shared__ float ared[4][64];                       // per-wave Wf partials

    const int tid  = threadIdx.x;
    const int b    = blockIdx.x;
    const int wv   = tid >> 6, lane = tid & 63;
    const int quad = lane >> 4, ln16 = lane & 15;

    const float4* in4 = (const float4*)(input + (size_t)b * Ln * En);
    const float4* pe4 = (const float4*)pos_enc;

    // ---- wave 0: speculative tile-0 x loads (rows 0..15, always valid) ----
    float4 px0 = {0,0,0,0}, px1 = {0,0,0,0}, px2 = {0,0,0,0}, px3 = {0,0,0,0};
    if (wv == 0) {
        const int o4 = ln16 * 16 + quad * 2;
        px0 = in4[o4];     px1 = in4[o4 + 1];
        px2 = in4[o4 + 8]; px3 = in4[o4 + 9];
    }

    // ---- mask loads (wave-local len; no barrier needed) ----
    const int* mb = mask + b * Ln;
    int c = (mb[lane] != 0) + (mb[64 + lane] != 0) + (mb[128 + lane] != 0)
          + ((lane < Ln - 192) ? (mb[192 + lane] != 0) : 0);

    // ---- B-fragments for ALL 4 heads (48 float4, L2/L1-hot) + biases ----
    f16x8 bfr[3][4][2];
    float bz[3][4];
    #pragma unroll
    for (int m = 0; m < 3; ++m) {
        const float* W = (m == 0) ? Wk : (m == 1) ? Wv : Wq;
        const float* B = (m == 0) ? bk : (m == 1) ? bv : bq;
        #pragma unroll
        for (int h = 0; h < 4; ++h) {
            #pragma unroll
            for (int ks = 0; ks < 2; ++ks) {
                const float4* wp = (const float4*)(W + (size_t)(h * 16 + ln16) * 64) + (ks * 8 + quad * 2);
                bfr[m][h][ks] = pack8(wp[0], wp[1]);
            }
            bz[m][h] = B[h * 16 + ln16];
        }
    }

    // ---- len (wave-local shuffle reduce) ----
    #pragma unroll
    for (int off = 32; off; off >>= 1) c += __shfl_down(c, off, 64);
    const int len = __shfl(c, 0, 64);
    const int nt = (len + 15) >> 4;

    // waves 1..3: first-tile x loads (rows wv*16+ln16 <= 63, always valid)
    if (wv != 0 && wv < nt) {
        const int o4 = (wv * 16 + ln16) * 16 + quad * 2;
        px0 = in4[o4];     px1 = in4[o4 + 1];
        px2 = in4[o4 + 8]; px3 = in4[o4 + 9];
    }

    // ---- merged projection: each wave does its row-tiles for ALL heads (24 MFMAs/tile) ----
    for (int rt = wv; rt < nt; rt += 4) {
        const int R = rt * 16 + ln16;
        const bool rok = (R < Ln);
        const int o4 = R * 16 + quad * 2;

        // next tile's x loads first (full iteration of latency cover)
        const int rtn = rt + 4;
        const int Rn = rtn * 16 + ln16;
        float4 pxn0 = {0,0,0,0}, pxn1 = {0,0,0,0}, pxn2 = {0,0,0,0}, pxn3 = {0,0,0,0};
        if (rtn < nt && Rn < Ln) {
            const int o4n = Rn * 16 + quad * 2;
            pxn0 = in4[o4n];     pxn1 = in4[o4n + 1];
            pxn2 = in4[o4n + 8]; pxn3 = in4[o4n + 9];
        }
        float4 pp0 = {0,0,0,0}, pp1 = {0,0,0,0}, pp2 = {0,0,0,0}, pp3 = {0,0,0,0};
        if (rok) {
            pp0 = pe4[o4];     pp1 = pe4[o4 + 1];
            pp2 = pe4[o4 + 8]; pp3 = pe4[o4 + 9];
        }
        const f16x8 af0 = pack8s(px0, px1, pp0, pp1);
        const f16x8 af1 = pack8s(px2, px3, pp2, pp3);

        f32x4 acc[3][4];
        #pragma unroll
        for (int m = 0; m < 3; ++m)
            #pragma unroll
            for (int h = 0; h < 4; ++h)
                acc[m][h] = (f32x4){bz[m][h], bz[m][h], bz[m][h], bz[m][h]};   // bias as C-init
        #pragma unroll
        for (int m = 0; m < 3; ++m)
            #pragma unroll
            for (int h = 0; h < 4; ++h)
                acc[m][h] = __builtin_amdgcn_mfma_f32_16x16x32_f16(af0, bfr[m][h][0], acc[m][h], 0, 0, 0);
        #pragma unroll
        for (int m = 0; m < 3; ++m)
            #pragma unroll
            for (int h = 0; h < 4; ++h)
                acc[m][h] = __builtin_amdgcn_mfma_f32_16x16x32_f16(af1, bfr[m][h][1], acc[m][h], 0, 0, 0);

        #pragma unroll
        for (int j = 0; j < 4; ++j) {
            const int t = rt * 16 + quad * 4 + j;
            if (t < Ln) {
                #pragma unroll
                for (int h = 0; h < 4; ++h) {
                    KhA[h][t * KS + ln16] = (__f16)acc[0][h][j];
                    QhA[h][t * KS + ln16] = (__f16)(acc[2][h][j] * QSC);
                }
            }
        }
        const int vc0 = rt * 16 + quad * 4;
        if (vc0 < Ln) {   // vc0 multiple of 4 -> vc0 <= 196 -> f16x4 in bounds
            #pragma unroll
            for (int h = 0; h < 4; ++h) {
                f16x4 vp;
                #pragma unroll
                for (int j = 0; j < 4; ++j) vp[j] = (__f16)acc[1][h][j];
                *(f16x4*)(&VtA[h][ln16 * VS + vc0]) = vp;
            }
        }
        px0 = pxn0; px1 = pxn1; px2 = pxn2; px3 = pxn3;
    }
    __syncthreads();   // K/Q/V (all heads) visible

    // ---- attention: wave wv owns head wv; loops its q-quads over all keys (nkh = 1) ----
    const __f16* Kh_ = KhA[wv];
    const __f16* Qh_ = QhA[wv];
    const __f16* Vt_ = VtA[wv];
    const int nquad = (nt + 3) >> 2;

    f32x4 pool = {0.f, 0.f, 0.f, 0.f};
    for (int g = 0; g < nquad; ++g) {
        const int qt0 = 4 * g;
        f32x4 o2[4], lacc[4];
        #pragma unroll
        for (int i = 0; i < 4; ++i) { o2[i] = (f32x4){0,0,0,0}; lacc[i] = (f32x4){0,0,0,0}; }
        const int ni = __builtin_amdgcn_readfirstlane(min(4, nt - qt0));
        switch (ni) {
            case 1:  attn_core<1>(Kh_, Qh_, Vt_, qt0, nt, len, quad, ln16, o2, lacc); break;
            case 2:  attn_core<2>(Kh_, Qh_, Vt_, qt0, nt, len, quad, ln16, o2, lacc); break;
            case 3:  attn_core<3>(Kh_, Qh_, Vt_, qt0, nt, len, quad, ln16, o2, lacc); break;
            default: attn_core<4>(Kh_, Qh_, Vt_, qt0, nt, len, quad, ln16, o2, lacc); break;
        }
        // fold this quad into the pooled sum (denominators wave-local: lacc[i][0] = l[q=ln16])
        #pragma unroll
        for (int i = 0; i < 4; ++i) {
            const float rs = ((qt0 + i) * 16 + ln16 < len) ? 1.f / lacc[i][0] : 0.f;
            #pragma unroll
            for (int j = 0; j < 4; ++j) pool[j] = fmaf(o2[i][j], rs, pool[j]);
        }
    }

    // ---- reduce pool over the 16 q-lanes; wave-local transpose; per-wave Wf partial ----
    #pragma unroll
    for (int j = 0; j < 4; ++j) {
        #pragma unroll
        for (int off = 1; off < 16; off <<= 1) pool[j] += __shfl_xor(pool[j], off, 64);
    }
    if (ln16 == 0) {
        #pragma unroll
        for (int j = 0; j < 4; ++j) swr[wv][quad * 4 + j] = pool[j];
    }
    float phv[16];
    #pragma unroll
    for (int i = 0; i < 16; ++i) phv[i] = swr[wv][i];   // same-wave RAW: compiler-ordered

    const float invlen = 1.f / ((float)len + 1e-8f);
    const float* wr = Wf + (size_t)lane * En + wv * 16;
    float a = 0.f;
    #pragma unroll
    for (int i = 0; i < 16; ++i) a = fmaf(wr[i], phv[i], a);
    ared[wv][lane] = a * invlen;
    __syncthreads();

    // ---- combine 4 head-partials + bias; single coalesced store (no atomics, no memset) ----
    if (tid < 64)
        out[b * En + tid] = bf_[tid] + ared[0][tid] + ared[1][tid] + ared[2][tid] + ared[3][tid];
}

extern "C" void kernel_launch(void* const* d_in, const int* in_sizes, int n_in,
                              void* d_out, int out_size, void* d_ws, size_t ws_size,
                              hipStream_t stream) {
    const float* input   = (const float*)d_in[0];
    const int*   mask    = (const int*)  d_in[1];
    const float* pos_enc = (const float*)d_in[2];
    const float* Wk      = (const float*)d_in[3];
    const float* bk      = (const float*)d_in[4];
    const float* Wv      = (const float*)d_in[5];
    const float* bv      = (const float*)d_in[6];
    const float* Wq      = (const float*)d_in[7];
    const float* bq      = (const float*)d_in[8];
    const float* Wf      = (const float*)d_in[9];
    const float* bf      = (const float*)d_in[10];

    float* out = (float*)d_out;

    // one block per b; out fully written by the kernel (no memset needed)
    fused_kernel<<<Bn, 256, 0, stream>>>(input, mask, pos_enc,
                                         Wk, bk, Wv, bv, Wq, bq, Wf, bf, out);
}